// Round 2
// baseline (2692.713 us; speedup 1.0000x reference)
//
#include <hip/hip_runtime.h>
#include <hip/hip_bf16.h>

#define NN 100000
#define NE 3200000
#define IND 128
#define ED 16
#define HD 64
#define NL 3
#define NG 256
#define BN_EPS 1e-5f

#define EDGE_BLOCKS 4096
#define MLP_BLOCKS 2048
#define APPLY_BLOCKS 2048

// ---------------- node projection: h = x @ np_w + np_b ----------------
// wave per node; x row staged in LDS; w columns from L1 (32KB, hot).
__global__ __launch_bounds__(256) void k_node_proj(
    const float* __restrict__ x, const float* __restrict__ w,
    const float* __restrict__ b, float* __restrict__ h)
{
    __shared__ float xs[4][IND];
    const int wave = threadIdx.x >> 6, lane = threadIdx.x & 63;
    const int node = blockIdx.x * 4 + wave;   // grid = NN/4 exactly
    xs[wave][lane]      = x[node * IND + lane];
    xs[wave][lane + 64] = x[node * IND + 64 + lane];
    // same-wave LDS write->read: hardware-ordered per wave
    float acc = b[lane];
#pragma unroll
    for (int k = 0; k < IND; ++k)
        acc = fmaf(xs[wave][k], w[k * HD + lane], acc);
    h[node * HD + lane] = acc;
}

// ---------------- edge message + scatter ----------------
// wave per edge (grid-stride). Edge id made wave-uniform via readfirstlane
// so edge_attr row + indices scalarize to SMEM loads. ep_w column (16 f32)
// held in registers. h gather is a coalesced 256B vector load; scatter is
// 64-lane contiguous f32 atomicAdd.
__global__ __launch_bounds__(256) void k_edge_msg(
    const float* __restrict__ ea, const int* __restrict__ ei,
    const float* __restrict__ epw, const float* __restrict__ epb,
    const float* __restrict__ h, float* __restrict__ agg)
{
    const int lane = threadIdx.x & 63;
    float wr[ED];
#pragma unroll
    for (int k = 0; k < ED; ++k) wr[k] = epw[k * HD + lane];
    const float bc = epb[lane];

    int wid = (blockIdx.x << 2) + (threadIdx.x >> 6);
    wid = __builtin_amdgcn_readfirstlane(wid);
    const int nw = EDGE_BLOCKS * 4;
    for (int e = wid; e < NE; e += nw) {
        const int src = ei[e];
        const int dst = ei[NE + e];
        float acc = bc;
#pragma unroll
        for (int k = 0; k < ED; ++k)
            acc = fmaf(ea[e * ED + k], wr[k], acc);
        float m = fmaxf(h[src * HD + lane] + acc, 0.f);
        atomicAdd(&agg[dst * HD + lane], m);
    }
}

// ---------------- per-layer MLP + BN partial stats ----------------
// wave per node; z0/t1 rows staged in LDS (same-wave exchange).
// t2 written IN PLACE over agg (each element touched by exactly one thread).
__global__ __launch_bounds__(256) void k_mlp(
    const float* __restrict__ h, float* agg_t2,
    const float* __restrict__ w1, const float* __restrict__ b1,
    const float* __restrict__ w2, const float* __restrict__ b2,
    float* __restrict__ part)
{
    __shared__ float z0s[4][HD];
    __shared__ float t1s[4][HD];
    __shared__ float red[4][2][HD];
    const int wave = threadIdx.x >> 6, lane = threadIdx.x & 63;
    const float vb1 = b1[lane], vb2 = b2[lane];
    float s1 = 0.f, s2 = 0.f;
    for (int node = blockIdx.x * 4 + wave; node < NN; node += MLP_BLOCKS * 4) {
        const int idx = node * HD + lane;
        z0s[wave][lane] = h[idx] + agg_t2[idx];
        float a = vb1;
#pragma unroll
        for (int k = 0; k < HD; ++k)
            a = fmaf(z0s[wave][k], w1[k * HD + lane], a);
        a = fmaxf(a, 0.f);
        t1s[wave][lane] = a;
        float o = vb2;
#pragma unroll
        for (int k = 0; k < HD; ++k)
            o = fmaf(t1s[wave][k], w2[k * HD + lane], o);
        agg_t2[idx] = o;
        s1 += o;
        s2 += o * o;
    }
    red[wave][0][lane] = s1;
    red[wave][1][lane] = s2;
    __syncthreads();
    if (wave == 0) {
        float a = red[0][0][lane] + red[1][0][lane] + red[2][0][lane] + red[3][0][lane];
        float c = red[0][1][lane] + red[1][1][lane] + red[2][1][lane] + red[3][1][lane];
        part[blockIdx.x * 128 + lane] = a;
        part[blockIdx.x * 128 + 64 + lane] = c;
    }
}

// ---------------- BN stats finalize: per-column scale/shift ----------------
__global__ void k_bn_final(const float* __restrict__ part,
                           const float* __restrict__ g, const float* __restrict__ b,
                           float* __restrict__ bnp)
{
    const int c = threadIdx.x;  // 64 threads
    float s1 = 0.f, s2 = 0.f;
    for (int i = 0; i < MLP_BLOCKS; ++i) {
        s1 += part[i * 128 + c];
        s2 += part[i * 128 + 64 + c];
    }
    const float mu  = s1 / (float)NN;
    const float var = s2 / (float)NN - mu * mu;
    const float rstd = rsqrtf(var + BN_EPS);
    const float sc = rstd * g[c];
    bnp[c] = sc;
    bnp[64 + c] = b[c] - mu * sc;
}

// ---------------- BN apply + ReLU, h lives in d_out (f32) ----------------
__global__ __launch_bounds__(256) void k_bn_apply(
    const float* __restrict__ t2, const float* __restrict__ bnp,
    float* __restrict__ h)
{
    const int lane = threadIdx.x & 63;
    const float sc = bnp[lane];
    const float sh = bnp[64 + lane];
    int i = blockIdx.x * 256 + threadIdx.x;
    const int stride = APPLY_BLOCKS * 256;
    for (; i < NN * HD; i += stride)
        h[i] = fmaxf(t2[i] * sc + sh, 0.f);
}

// ---------------- global mean pool (batch is sorted) ----------------
__global__ __launch_bounds__(64) void k_pool(
    const float* __restrict__ h, const int* __restrict__ batch,
    float* __restrict__ emb)
{
    const int g = blockIdx.x, lane = threadIdx.x;
    int lo = 0, hi = NN;
    while (lo < hi) { int m = (lo + hi) >> 1; if (batch[m] < g) lo = m + 1; else hi = m; }
    const int start = lo;
    hi = NN;
    while (lo < hi) { int m = (lo + hi) >> 1; if (batch[m] <= g) lo = m + 1; else hi = m; }
    const int end = lo;
    float acc = 0.f;
    for (int n = start; n < end; ++n) acc += h[n * HD + lane];
    emb[g * HD + lane] = acc / fmaxf((float)(end - start), 1.f);
}

extern "C" void kernel_launch(void* const* d_in, const int* in_sizes, int n_in,
                              void* d_out, int out_size, void* d_ws, size_t ws_size,
                              hipStream_t stream)
{
    const float* x     = (const float*)d_in[0];
    const float* ea    = (const float*)d_in[1];
    const int*   ei    = (const int*)d_in[2];
    const int*   batch = (const int*)d_in[3];
    const float* np_w  = (const float*)d_in[4];
    const float* np_b  = (const float*)d_in[5];
    const float* ep_w  = (const float*)d_in[6];
    const float* ep_b  = (const float*)d_in[7];
    const float* w1    = (const float*)d_in[8];
    const float* b1    = (const float*)d_in[9];
    const float* w2    = (const float*)d_in[10];
    const float* b2    = (const float*)d_in[11];
    const float* bng   = (const float*)d_in[12];
    const float* bnb   = (const float*)d_in[13];

    // h lives directly in d_out (f32): [NN*HD] then graph_emb [NG*HD]
    float* h   = (float*)d_out;
    float* emb = h + (size_t)NN * HD;

    char* ws = (char*)d_ws;
    float* agg  = (float*)(ws);               // 25,600,000 B; doubles as t2
    float* part = (float*)(ws + 25600000);    // 1,048,576 B
    float* bnp  = (float*)(ws + 26648576);    // 512 B

    k_node_proj<<<NN / 4, 256, 0, stream>>>(x, np_w, np_b, h);

    for (int l = 0; l < NL; ++l) {
        hipMemsetAsync(agg, 0, (size_t)NN * HD * sizeof(float), stream);
        k_edge_msg<<<EDGE_BLOCKS, 256, 0, stream>>>(ea, ei, ep_w, ep_b, h, agg);
        k_mlp<<<MLP_BLOCKS, 256, 0, stream>>>(h, agg, w1 + l * HD * HD, b1 + l * HD,
                                              w2 + l * HD * HD, b2 + l * HD, part);
        k_bn_final<<<1, 64, 0, stream>>>(part, bng + l * HD, bnb + l * HD, bnp);
        k_bn_apply<<<APPLY_BLOCKS, 256, 0, stream>>>(agg, bnp, h);
    }

    k_pool<<<NG, 64, 0, stream>>>(h, batch, emb);
}

// Round 3
// 1848.075 us; speedup vs baseline: 1.4570x; 1.4570x over previous
//
#include <hip/hip_runtime.h>
#include <hip/hip_bf16.h>

#define NN 100000
#define NE 3200000
#define IND 128
#define ED 16
#define HD 64
#define NL 3
#define NG 256
#define BN_EPS 1e-5f

#define EDGE_BLOCKS 4096
#define MLP_BLOCKS 2048
#define APPLY_BLOCKS 2048

// ================= node projection: h = x @ np_w + np_b =================
__global__ __launch_bounds__(256) void k_node_proj(
    const float* __restrict__ x, const float* __restrict__ w,
    const float* __restrict__ b, float* __restrict__ h)
{
    __shared__ float xs[4][IND];
    const int wave = threadIdx.x >> 6, lane = threadIdx.x & 63;
    const int node = blockIdx.x * 4 + wave;   // grid = NN/4 exactly
    xs[wave][lane]      = x[node * IND + lane];
    xs[wave][lane + 64] = x[node * IND + 64 + lane];
    // same-wave LDS write->read: hardware-ordered per wave
    float acc = b[lane];
#pragma unroll
    for (int k = 0; k < IND; ++k)
        acc = fmaf(xs[wave][k], w[k * HD + lane], acc);
    h[node * HD + lane] = acc;
}

// ================= CSR preprocessing =================
// 1) degree histogram over dst
__global__ __launch_bounds__(256) void k_hist(const int* __restrict__ ei,
                                              int* __restrict__ deg)
{
    const int e = blockIdx.x * 256 + threadIdx.x;   // grid = NE/256 exactly
    atomicAdd(&deg[ei[NE + e]], 1);
}

// 2) exclusive prefix sum -> rowptr[NN+1], cur[NN]
#define SCAN_T 1024
#define SCAN_C 98   // ceil(NN / SCAN_T)
__global__ __launch_bounds__(SCAN_T) void k_scan(const int* __restrict__ deg,
                                                 int* __restrict__ rowptr,
                                                 int* __restrict__ cur)
{
    __shared__ int ps[SCAN_T];
    const int t = threadIdx.x;
    const int begin = t * SCAN_C;
    const int end = min(begin + SCAN_C, NN);
    int s = 0;
    for (int i = begin; i < end; ++i) s += deg[i];
    ps[t] = s;
    __syncthreads();
    for (int off = 1; off < SCAN_T; off <<= 1) {
        int v = (t >= off) ? ps[t - off] : 0;
        __syncthreads();
        ps[t] += v;
        __syncthreads();
    }
    int run = (t == 0) ? 0 : ps[t - 1];
    for (int i = begin; i < end; ++i) {
        rowptr[i] = run;
        cur[i] = run;
        run += deg[i];
    }
    if (t == SCAN_T - 1) rowptr[NN] = run;   // == NE (this thread's range is empty)
}

// 3) scatter edges into dst-sorted order.
// MODE 0: copy edge_attr row (sequential reads per layer later)
// MODE 1: store edge id only (random scalar ea reads per layer later)
template <int MODE>
__global__ __launch_bounds__(256) void k_scatter(
    const int* __restrict__ ei, const float* __restrict__ ea,
    int* __restrict__ cur, int* __restrict__ perm_src,
    float* __restrict__ ea_perm, int* __restrict__ perm_eid)
{
    const int e = blockIdx.x * 256 + threadIdx.x;   // grid = NE/256 exactly
    const int dst = ei[NE + e];
    const int src = ei[e];
    const int pos = atomicAdd(&cur[dst], 1);
    perm_src[pos] = src;
    if constexpr (MODE == 0) {
        const float4* s4 = (const float4*)(ea + (size_t)e * ED);
        float4* d4 = (float4*)(ea_perm + (size_t)pos * ED);
        d4[0] = s4[0]; d4[1] = s4[1]; d4[2] = s4[2]; d4[3] = s4[3];
    } else {
        perm_eid[pos] = e;
    }
}

// ================= gather aggregation =================
// wave per node (lane = column). All edge-side loads are wave-uniform ->
// scalar (SMEM) loads; h gather is a 256B coalesced vector load per edge.
// Writes z = h[node] + sum_j relu(h[src_j] + eproj_j). No atomics.
template <int MODE>
__global__ __launch_bounds__(256) void k_gather(
    const float* __restrict__ eadata, const int* __restrict__ perm_src,
    const int* __restrict__ perm_eid, const int* __restrict__ rowptr,
    const float* __restrict__ epw, const float* __restrict__ epb,
    const float* __restrict__ h, float* __restrict__ z)
{
    const int lane = threadIdx.x & 63;
    float wr[ED];
#pragma unroll
    for (int k = 0; k < ED; ++k) wr[k] = epw[k * HD + lane];
    const float bc = epb[lane];

    const int node = __builtin_amdgcn_readfirstlane((blockIdx.x << 2) + (threadIdx.x >> 6));
    const int rs = rowptr[node];
    const int re = rowptr[node + 1];

    float acc = 0.f;
    int j = rs;
    for (; j + 2 <= re; j += 2) {
        int i0, i1;
        if constexpr (MODE == 1) { i0 = perm_eid[j]; i1 = perm_eid[j + 1]; }
        else                     { i0 = j;           i1 = j + 1; }
        const float* r0 = eadata + (size_t)i0 * ED;
        const float* r1 = eadata + (size_t)i1 * ED;
        const int s0 = perm_src[j];
        const int s1 = perm_src[j + 1];
        float e0 = bc, e1 = bc;
#pragma unroll
        for (int k = 0; k < ED; ++k) {
            e0 = fmaf(r0[k], wr[k], e0);
            e1 = fmaf(r1[k], wr[k], e1);
        }
        acc += fmaxf(h[(size_t)s0 * HD + lane] + e0, 0.f);
        acc += fmaxf(h[(size_t)s1 * HD + lane] + e1, 0.f);
    }
    if (j < re) {
        const int i0 = (MODE == 1) ? perm_eid[j] : j;
        const float* r0 = eadata + (size_t)i0 * ED;
        const int s0 = perm_src[j];
        float e0 = bc;
#pragma unroll
        for (int k = 0; k < ED; ++k) e0 = fmaf(r0[k], wr[k], e0);
        acc += fmaxf(h[(size_t)s0 * HD + lane] + e0, 0.f);
    }
    const int idx = node * HD + lane;
    z[idx] = acc + h[idx];
}

// ================= fallback: atomic edge scatter (round-1 path) ===========
__global__ __launch_bounds__(256) void k_edge_msg(
    const float* __restrict__ ea, const int* __restrict__ ei,
    const float* __restrict__ epw, const float* __restrict__ epb,
    const float* __restrict__ h, float* __restrict__ agg)
{
    const int lane = threadIdx.x & 63;
    float wr[ED];
#pragma unroll
    for (int k = 0; k < ED; ++k) wr[k] = epw[k * HD + lane];
    const float bc = epb[lane];

    int wid = (blockIdx.x << 2) + (threadIdx.x >> 6);
    wid = __builtin_amdgcn_readfirstlane(wid);
    const int nw = EDGE_BLOCKS * 4;
    for (int e = wid; e < NE; e += nw) {
        const int src = ei[e];
        const int dst = ei[NE + e];
        float acc = bc;
#pragma unroll
        for (int k = 0; k < ED; ++k)
            acc = fmaf(ea[e * ED + k], wr[k], acc);
        float m = fmaxf(h[src * HD + lane] + acc, 0.f);
        atomicAdd(&agg[dst * HD + lane], m);
    }
}

// ================= per-layer MLP + BN partial stats =================
// ADD_H: z0 = h + zin (atomic path) vs z0 = zin (CSR path, h already added)
template <bool ADD_H>
__global__ __launch_bounds__(256) void k_mlp(
    const float* __restrict__ h, float* zin_t2,
    const float* __restrict__ w1, const float* __restrict__ b1,
    const float* __restrict__ w2, const float* __restrict__ b2,
    float* __restrict__ part)
{
    __shared__ float z0s[4][HD];
    __shared__ float t1s[4][HD];
    __shared__ float red[4][2][HD];
    const int wave = threadIdx.x >> 6, lane = threadIdx.x & 63;
    const float vb1 = b1[lane], vb2 = b2[lane];
    float s1 = 0.f, s2 = 0.f;
    for (int node = blockIdx.x * 4 + wave; node < NN; node += MLP_BLOCKS * 4) {
        const int idx = node * HD + lane;
        z0s[wave][lane] = ADD_H ? (h[idx] + zin_t2[idx]) : zin_t2[idx];
        float a = vb1;
#pragma unroll
        for (int k = 0; k < HD; ++k)
            a = fmaf(z0s[wave][k], w1[k * HD + lane], a);
        a = fmaxf(a, 0.f);
        t1s[wave][lane] = a;
        float o = vb2;
#pragma unroll
        for (int k = 0; k < HD; ++k)
            o = fmaf(t1s[wave][k], w2[k * HD + lane], o);
        zin_t2[idx] = o;
        s1 += o;
        s2 += o * o;
    }
    red[wave][0][lane] = s1;
    red[wave][1][lane] = s2;
    __syncthreads();
    if (wave == 0) {
        float a = red[0][0][lane] + red[1][0][lane] + red[2][0][lane] + red[3][0][lane];
        float c = red[0][1][lane] + red[1][1][lane] + red[2][1][lane] + red[3][1][lane];
        part[blockIdx.x * 128 + lane] = a;
        part[blockIdx.x * 128 + 64 + lane] = c;
    }
}

// ================= BN stats finalize (parallel, 1 block x 1024) ===========
__global__ __launch_bounds__(1024) void k_bn_final(
    const float* __restrict__ part,
    const float* __restrict__ g, const float* __restrict__ b,
    float* __restrict__ bnp)
{
    __shared__ float red[16][2][HD];
    const int c = threadIdx.x & 63;       // column
    const int s = threadIdx.x >> 6;       // slice 0..15
    float s1 = 0.f, s2 = 0.f;
    for (int i = s; i < MLP_BLOCKS; i += 16) {
        s1 += part[i * 128 + c];
        s2 += part[i * 128 + 64 + c];
    }
    red[s][0][c] = s1;
    red[s][1][c] = s2;
    __syncthreads();
    if (s == 0) {
        float a = 0.f, q = 0.f;
#pragma unroll
        for (int i = 0; i < 16; ++i) { a += red[i][0][c]; q += red[i][1][c]; }
        const float mu  = a / (float)NN;
        const float var = q / (float)NN - mu * mu;
        const float rstd = rsqrtf(var + BN_EPS);
        const float sc = rstd * g[c];
        bnp[c] = sc;
        bnp[64 + c] = b[c] - mu * sc;
    }
}

// ================= BN apply + ReLU (h lives in d_out, f32) =================
__global__ __launch_bounds__(256) void k_bn_apply(
    const float* __restrict__ t2, const float* __restrict__ bnp,
    float* __restrict__ h)
{
    const int lane = threadIdx.x & 63;
    const float sc = bnp[lane];
    const float sh = bnp[64 + lane];
    int i = blockIdx.x * 256 + threadIdx.x;
    const int stride = APPLY_BLOCKS * 256;
    for (; i < NN * HD; i += stride)
        h[i] = fmaxf(t2[i] * sc + sh, 0.f);
}

// ================= global mean pool (batch sorted) =================
__global__ __launch_bounds__(64) void k_pool(
    const float* __restrict__ h, const int* __restrict__ batch,
    float* __restrict__ emb)
{
    const int g = blockIdx.x, lane = threadIdx.x;
    int lo = 0, hi = NN;
    while (lo < hi) { int m = (lo + hi) >> 1; if (batch[m] < g) lo = m + 1; else hi = m; }
    const int start = lo;
    hi = NN;
    while (lo < hi) { int m = (lo + hi) >> 1; if (batch[m] <= g) lo = m + 1; else hi = m; }
    const int end = lo;
    float acc = 0.f;
    for (int n = start; n < end; ++n) acc += h[n * HD + lane];
    emb[g * HD + lane] = acc / fmaxf((float)(end - start), 1.f);
}

extern "C" void kernel_launch(void* const* d_in, const int* in_sizes, int n_in,
                              void* d_out, int out_size, void* d_ws, size_t ws_size,
                              hipStream_t stream)
{
    const float* x     = (const float*)d_in[0];
    const float* ea    = (const float*)d_in[1];
    const int*   ei    = (const int*)d_in[2];
    const int*   batch = (const int*)d_in[3];
    const float* np_w  = (const float*)d_in[4];
    const float* np_b  = (const float*)d_in[5];
    const float* ep_w  = (const float*)d_in[6];
    const float* ep_b  = (const float*)d_in[7];
    const float* w1    = (const float*)d_in[8];
    const float* b1    = (const float*)d_in[9];
    const float* w2    = (const float*)d_in[10];
    const float* b2    = (const float*)d_in[11];
    const float* bng   = (const float*)d_in[12];
    const float* bnb   = (const float*)d_in[13];

    // h lives directly in d_out (f32): [NN*HD] then graph_emb [NG*HD]
    float* h   = (float*)d_out;
    float* emb = h + (size_t)NN * HD;

    char* ws = (char*)d_ws;
    float* agg      = (float*)(ws);                 // 25,600,000 (z / t2)
    float* part     = (float*)(ws + 25600000);      //  1,048,576
    float* bnp      = (float*)(ws + 26648576);      //        512
    int*   deg      = (int*)  (ws + 26649088);      //    400,000
    int*   rowptr   = (int*)  (ws + 27049088);      //    400,016
    int*   cur      = (int*)  (ws + 27449104);      //    400,000
    int*   perm_src = (int*)  (ws + 27849104);      // 12,800,000
    float* ea_perm  = (float*)(ws + 40649104);      // 204,800,000 (mode 0)
    int*   perm_eid = (int*)  (ws + 40649104);      //  12,800,000 (mode 1)

    const size_t NEED_A = 40649104u + 204800000u;   // ~245.4 MB
    const size_t NEED_B = 40649104u + 12800000u;    // ~53.4 MB
    const int mode = (ws_size >= NEED_A) ? 0 : (ws_size >= NEED_B) ? 1 : 2;

    k_node_proj<<<NN / 4, 256, 0, stream>>>(x, np_w, np_b, h);

    if (mode != 2) {
        hipMemsetAsync(deg, 0, NN * sizeof(int), stream);
        k_hist<<<NE / 256, 256, 0, stream>>>(ei, deg);
        k_scan<<<1, SCAN_T, 0, stream>>>(deg, rowptr, cur);
        if (mode == 0)
            k_scatter<0><<<NE / 256, 256, 0, stream>>>(ei, ea, cur, perm_src, ea_perm, perm_eid);
        else
            k_scatter<1><<<NE / 256, 256, 0, stream>>>(ei, ea, cur, perm_src, ea_perm, perm_eid);
    }

    for (int l = 0; l < NL; ++l) {
        if (mode == 0) {
            k_gather<0><<<NN / 4, 256, 0, stream>>>(ea_perm, perm_src, perm_eid,
                                                    rowptr, ep_w, ep_b, h, agg);
            k_mlp<false><<<MLP_BLOCKS, 256, 0, stream>>>(h, agg, w1 + l * HD * HD, b1 + l * HD,
                                                         w2 + l * HD * HD, b2 + l * HD, part);
        } else if (mode == 1) {
            k_gather<1><<<NN / 4, 256, 0, stream>>>(ea, perm_src, perm_eid,
                                                    rowptr, ep_w, ep_b, h, agg);
            k_mlp<false><<<MLP_BLOCKS, 256, 0, stream>>>(h, agg, w1 + l * HD * HD, b1 + l * HD,
                                                         w2 + l * HD * HD, b2 + l * HD, part);
        } else {
            hipMemsetAsync(agg, 0, (size_t)NN * HD * sizeof(float), stream);
            k_edge_msg<<<EDGE_BLOCKS, 256, 0, stream>>>(ea, ei, ep_w, ep_b, h, agg);
            k_mlp<true><<<MLP_BLOCKS, 256, 0, stream>>>(h, agg, w1 + l * HD * HD, b1 + l * HD,
                                                        w2 + l * HD * HD, b2 + l * HD, part);
        }
        k_bn_final<<<1, 1024, 0, stream>>>(part, bng + l * HD, bnb + l * HD, bnp);
        k_bn_apply<<<APPLY_BLOCKS, 256, 0, stream>>>(agg, bnp, h);
    }

    k_pool<<<NG, 64, 0, stream>>>(h, batch, emb);
}